// Round 1
// baseline (565.350 us; speedup 1.0000x reference)
//
#include <hip/hip_runtime.h>
#include <hip/hip_bf16.h>

#define B_ 2
#define C_ 20000
#define H_ 64
#define M_ 8
#define E_ 200000
#define P_ 3
#define EPS_ 1e-12f

__device__ __forceinline__ float silu_(float x) {
    return x / (1.f + __expf(-x));
}

// ---------------------------------------------------------------------------
// K1: per-(b,e) geometric invariants -> inv4[b][e] = {dist, pairwise, centroid, haus}
// One thread per (b,e). All gathers are L2-resident (positions 480KB, cni 640KB).
// ---------------------------------------------------------------------------
__global__ __launch_bounds__(256) void geom_kernel(
    const float* __restrict__ pos, const int* __restrict__ ei,
    const int* __restrict__ cni, const float* __restrict__ mask,
    float* __restrict__ inv4)
{
    int tid = blockIdx.x * 256 + threadIdx.x;
    if (tid >= B_ * E_) return;
    int b = tid / E_;
    int e = tid - b * E_;
    int s = ei[e];
    int d = ei[E_ + e];
    const float* pb = pos + (size_t)b * C_ * P_;

    float rx = pb[s*3+0] - pb[d*3+0];
    float ry = pb[s*3+1] - pb[d*3+1];
    float rz = pb[s*3+2] - pb[d*3+2];
    float dist = sqrtf(rx*rx + ry*ry + rz*rz);

    float spx[M_], spy[M_], spz[M_], dpx[M_], dpy[M_], dpz[M_];
    float mx[M_], my[M_], sp2[M_], dp2[M_];
    #pragma unroll
    for (int m = 0; m < M_; ++m) {
        int ns = cni[s*M_ + m];
        spx[m] = pb[ns*3+0]; spy[m] = pb[ns*3+1]; spz[m] = pb[ns*3+2];
        int nd = cni[d*M_ + m];
        dpx[m] = pb[nd*3+0]; dpy[m] = pb[nd*3+1]; dpz[m] = pb[nd*3+2];
        mx[m] = mask[s*M_ + m];
        my[m] = mask[d*M_ + m];
        sp2[m] = spx[m]*spx[m] + spy[m]*spy[m] + spz[m]*spz[m];
        dp2[m] = dpx[m]*dpx[m] + dpy[m]*dpy[m] + dpz[m]*dpz[m];
    }
    const float INFV = __builtin_inff();
    float pair = 0.f, hxy = 0.f;
    float colmin[M_];
    #pragma unroll
    for (int j = 0; j < M_; ++j) colmin[j] = INFV;
    #pragma unroll
    for (int i = 0; i < M_; ++i) {
        float rowmin = INFV;
        #pragma unroll
        for (int j = 0; j < M_; ++j) {
            float cr = spx[i]*dpx[j] + spy[i]*dpy[j] + spz[i]*dpz[j];
            float dd = sqrtf(fmaxf(sp2[i] + dp2[j] - 2.f*cr, 0.f) + EPS_);
            pair += dd * mx[i] * my[j];
            rowmin    = (my[j] > 0.f) ? fminf(rowmin, dd)    : rowmin;
            colmin[j] = (mx[i] > 0.f) ? fminf(colmin[j], dd) : colmin[j];
        }
        hxy = fmaxf(hxy, (mx[i] > 0.f) ? rowmin : 0.f);
    }
    float hyx = 0.f;
    #pragma unroll
    for (int j = 0; j < M_; ++j)
        hyx = fmaxf(hyx, (my[j] > 0.f) ? colmin[j] : 0.f);
    float haus = fmaxf(hxy, hyx);

    float smx = 0.f, smy = 0.f;
    float cxx=0.f, cxy=0.f, cxz=0.f, cyx=0.f, cyy=0.f, cyz=0.f;
    #pragma unroll
    for (int m = 0; m < M_; ++m) {
        smx += mx[m]; smy += my[m];
        cxx += spx[m]*mx[m]; cxy += spy[m]*mx[m]; cxz += spz[m]*mx[m];
        cyx += dpx[m]*my[m]; cyy += dpy[m]*my[m]; cyz += dpz[m]*my[m];
    }
    float idx_ = 1.f / fmaxf(smx, EPS_);
    float idy_ = 1.f / fmaxf(smy, EPS_);
    float ddx = cxx*idx_ - cyx*idy_;
    float ddy = cxy*idx_ - cyy*idy_;
    float ddz = cxz*idx_ - cyz*idy_;
    float centroid = sqrtf(ddx*ddx + ddy*ddy + ddz*ddz);

    ((float4*)inv4)[(size_t)b * E_ + e] = make_float4(dist, pair, centroid, haus);
}

// ---------------------------------------------------------------------------
// K2: edge MLPs + scatter. One wave (64 lanes) per 64-edge tile; lane = edge.
// GEMM-on-VALU with scalar (SGPR) weight broadcast: per k, 1 ds_read + 64 v_fmac.
// LDS tile stride 65 -> (lane+k)%32 banks -> 2-way aliasing (free per m136).
// Messages transposed through LDS so scatter atomics are coalesced 256B rows.
// ---------------------------------------------------------------------------
__global__ __launch_bounds__(64) void edge_kernel(
    const float* __restrict__ feat, const float* __restrict__ pos,
    const int* __restrict__ ei, const float* __restrict__ inv4,
    const float* __restrict__ W1, const float* __restrict__ b1,
    const float* __restrict__ W2, const float* __restrict__ b2,
    const float* __restrict__ P1, const float* __restrict__ pb1,
    const float* __restrict__ P2, const float* __restrict__ pb2,
    float* __restrict__ agg, float* __restrict__ out_pos)
{
    __shared__ float lds[64 * 65];
    const int lane = threadIdx.x;
    const int tile = blockIdx.x;
    const int b  = tile / (E_ / 64);
    const int e0 = (tile % (E_ / 64)) * 64;
    const int my_e = e0 + lane;
    const int s_l = ei[my_e];
    const int d_l = ei[E_ + my_e];
    const float* fb = feat + (size_t)b * C_ * H_;

    // stage h_src tile (coalesced row loads)
    for (int r = 0; r < 64; ++r) {
        int sr = __shfl(s_l, r);
        lds[r*65 + lane] = fb[(size_t)sr * 64 + lane];
    }
    __syncthreads();
    float acc[64];
    #pragma unroll
    for (int j = 0; j < 64; ++j) acc[j] = b1[j];
    for (int k = 0; k < 64; ++k) {
        float xk = lds[lane*65 + k];
        const float* w = W1 + k*64;
        #pragma unroll
        for (int j = 0; j < 64; ++j) acc[j] = fmaf(xk, w[j], acc[j]);
    }
    __syncthreads();
    // stage h_dst tile
    for (int r = 0; r < 64; ++r) {
        int dr = __shfl(d_l, r);
        lds[r*65 + lane] = fb[(size_t)dr * 64 + lane];
    }
    __syncthreads();
    for (int k = 0; k < 64; ++k) {
        float xk = lds[lane*65 + k];
        const float* w = W1 + (64 + k)*64;
        #pragma unroll
        for (int j = 0; j < 64; ++j) acc[j] = fmaf(xk, w[j], acc[j]);
    }
    // invariant columns 128..131
    float4 iv = ((const float4*)inv4)[(size_t)b * E_ + my_e];
    {
        const float* wa = W1 + 128*64;
        const float* wb = W1 + 129*64;
        const float* wc = W1 + 130*64;
        const float* wd = W1 + 131*64;
        #pragma unroll
        for (int j = 0; j < 64; ++j)
            acc[j] += iv.x*wa[j] + iv.y*wb[j] + iv.z*wc[j] + iv.w*wd[j];
    }
    __syncthreads();
    #pragma unroll
    for (int j = 0; j < 64; ++j) lds[lane*65 + j] = silu_(acc[j]);
    __syncthreads();
    // layer 2 -> messages
    float mm[64];
    #pragma unroll
    for (int j = 0; j < 64; ++j) mm[j] = b2[j];
    for (int k = 0; k < 64; ++k) {
        float xk = lds[lane*65 + k];
        const float* w = W2 + k*64;
        #pragma unroll
        for (int j = 0; j < 64; ++j) mm[j] = fmaf(xk, w[j], mm[j]);
    }
    __syncthreads();
    #pragma unroll
    for (int j = 0; j < 64; ++j) lds[lane*65 + j] = mm[j];  // messages stay here for scatter
    __syncthreads();
    // gate MLP: silu(m @ P1 + pb1) @ P2 + pb2 -> tanh
    float pacc[64];
    #pragma unroll
    for (int j = 0; j < 64; ++j) pacc[j] = pb1[j];
    for (int k = 0; k < 64; ++k) {
        float xk = lds[lane*65 + k];
        const float* w = P1 + k*64;
        #pragma unroll
        for (int j = 0; j < 64; ++j) pacc[j] = fmaf(xk, w[j], pacc[j]);
    }
    float wt = pb2[0];
    #pragma unroll
    for (int j = 0; j < 64; ++j) wt += silu_(pacc[j]) * P2[j];
    wt = tanhf(wt);

    // scatter: coalesced row atomics for agg, 3-lane atomics for positions
    float* aggb = agg + (size_t)b * C_ * H_;
    float* opb  = out_pos + (size_t)b * C_ * P_;
    const float* pb = pos + (size_t)b * C_ * P_;
    for (int r = 0; r < 64; ++r) {
        int dr = __shfl(d_l, r);
        int sr = __shfl(s_l, r);
        float wtr = __shfl(wt, r);
        float v = lds[r*65 + lane];
        atomicAdd(&aggb[(size_t)dr*64 + lane], v);
        if (lane < 3) {
            float relp = pb[sr*3 + lane] - pb[dr*3 + lane];
            atomicAdd(&opb[dr*3 + lane], wtr * relp);
        }
    }
}

// ---------------------------------------------------------------------------
// K3: node update. Rows g = b*C + c are flat; lane = row within a 64-row tile.
// new_features = features + MLP([features, agg/max(deg,1)])
// ---------------------------------------------------------------------------
__global__ __launch_bounds__(64) void node_kernel(
    const float* __restrict__ feat, const float* __restrict__ agg,
    const float* __restrict__ deg,
    const float* __restrict__ U1, const float* __restrict__ ub1,
    const float* __restrict__ U2, const float* __restrict__ ub2,
    float* __restrict__ out_feat)
{
    __shared__ float lds[64 * 129];
    const int lane = threadIdx.x;
    const int g0 = blockIdx.x * 64;
    for (int r = 0; r < 64; ++r) {
        int g = g0 + r;
        float dg = deg[g % C_];                 // uniform -> scalar load
        float sc = 1.f / fmaxf(dg, 1.f);
        lds[r*129 + lane]      = feat[(size_t)g*64 + lane];
        lds[r*129 + 64 + lane] = agg[(size_t)g*64 + lane] * sc;
    }
    __syncthreads();
    float acc[64];
    #pragma unroll
    for (int j = 0; j < 64; ++j) acc[j] = ub1[j];
    for (int k = 0; k < 128; ++k) {
        float xk = lds[lane*129 + k];
        const float* w = U1 + k*64;
        #pragma unroll
        for (int j = 0; j < 64; ++j) acc[j] = fmaf(xk, w[j], acc[j]);
    }
    __syncthreads();
    #pragma unroll
    for (int j = 0; j < 64; ++j) lds[lane*129 + j] = silu_(acc[j]);
    __syncthreads();
    float o[64];
    #pragma unroll
    for (int j = 0; j < 64; ++j) o[j] = ub2[j];
    for (int k = 0; k < 64; ++k) {
        float xk = lds[lane*129 + k];
        const float* w = U2 + k*64;
        #pragma unroll
        for (int j = 0; j < 64; ++j) o[j] = fmaf(xk, w[j], o[j]);
    }
    __syncthreads();
    #pragma unroll
    for (int j = 0; j < 64; ++j) lds[lane*129 + j] = o[j];
    __syncthreads();
    for (int r = 0; r < 64; ++r) {
        size_t idx = (size_t)(g0 + r) * 64 + lane;
        out_feat[idx] = feat[idx] + lds[r*129 + lane];
    }
}

extern "C" void kernel_launch(void* const* d_in, const int* in_sizes, int n_in,
                              void* d_out, int out_size, void* d_ws, size_t ws_size,
                              hipStream_t stream) {
    const float* feat = (const float*)d_in[0];
    const float* pos  = (const float*)d_in[1];
    const int*   ei   = (const int*)d_in[2];
    const float* deg  = (const float*)d_in[3];
    const int*   cni  = (const int*)d_in[4];
    const float* mask = (const float*)d_in[5];
    const float* W1   = (const float*)d_in[6];
    const float* b1   = (const float*)d_in[7];
    const float* W2   = (const float*)d_in[8];
    const float* b2   = (const float*)d_in[9];
    const float* P1   = (const float*)d_in[10];
    const float* pb1  = (const float*)d_in[11];
    const float* P2   = (const float*)d_in[12];
    const float* pb2  = (const float*)d_in[13];
    const float* U1   = (const float*)d_in[14];
    const float* ub1  = (const float*)d_in[15];
    const float* U2   = (const float*)d_in[16];
    const float* ub2  = (const float*)d_in[17];

    float* out_feat = (float*)d_out;                       // B*C*H
    float* out_pos  = out_feat + (size_t)B_ * C_ * H_;     // B*C*P

    // workspace: inv4 (B*E*4 floats) | agg (B*C*H floats)  -> 16.64 MB total
    float* inv4 = (float*)d_ws;
    float* agg  = inv4 + (size_t)B_ * E_ * 4;

    hipMemsetAsync(agg, 0, (size_t)B_ * C_ * H_ * sizeof(float), stream);
    hipMemcpyAsync(out_pos, pos, (size_t)B_ * C_ * P_ * sizeof(float),
                   hipMemcpyDeviceToDevice, stream);

    geom_kernel<<<(B_ * E_ + 255) / 256, 256, 0, stream>>>(pos, ei, cni, mask, inv4);

    edge_kernel<<<(B_ * E_) / 64, 64, 0, stream>>>(
        feat, pos, ei, inv4, W1, b1, W2, b2, P1, pb1, P2, pb2, agg, out_pos);

    node_kernel<<<(B_ * C_) / 64, 64, 0, stream>>>(
        feat, agg, deg, U1, ub1, U2, ub2, out_feat);
}

// Round 2
// 319.921 us; speedup vs baseline: 1.7672x; 1.7672x over previous
//
#include <hip/hip_runtime.h>
#include <hip/hip_bf16.h>

#define B_ 2
#define C_ 20000
#define H_ 64
#define M_ 8
#define E_ 200000
#define P_ 3
#define EPS_ 1e-12f

typedef __attribute__((ext_vector_type(8))) short short8;
typedef __attribute__((ext_vector_type(4))) float float4v;

__device__ __forceinline__ float silu_(float x) {
    return x / (1.f + __expf(-x));
}
__device__ __forceinline__ unsigned short f2b(float f) {
    unsigned u = __float_as_uint(f);
    unsigned r = (u + 0x7FFF + ((u >> 16) & 1)) >> 16;   // RNE fp32->bf16
    return (unsigned short)r;
}
__device__ __forceinline__ float b2f(unsigned short h) {
    return __uint_as_float(((unsigned)h) << 16);
}

// workspace layout (floats then bf16):
//   inv4 : B*E*4 fp32
//   agg  : B*C*H fp32
//   wbuf : 30720 bf16 (u16) swizzled weight fragments
//     W1s [0,10240)  5kk x 4nt   (K padded 132->160)
//     W2s [10240,14336)  2kk x 4nt
//     P1s [14336,18432)  2kk x 4nt
//     U1s [18432,26624)  4kk x 4nt
//     U2s [26624,30720)  2kk x 4nt
#define W1S_OFF 0
#define W2S_OFF 10240
#define P1S_OFF 14336
#define U1S_OFF 18432
#define U2S_OFF 26624
#define WBUF_ELEMS 30720

// ---------------------------------------------------------------------------
// prep: fp32 weights -> bf16 B-fragment-swizzled layout.
// B-frag for 16x16x32: lane holds B[k=kk*32+(lane>>4)*8+j][n=nt*16+(lane&15)],
// j=0..7 contiguous -> element index e = kk*2048 + nt*512 + lane*8 + j.
// ---------------------------------------------------------------------------
__global__ __launch_bounds__(256) void prep_kernel(
    const float* __restrict__ W1, const float* __restrict__ W2,
    const float* __restrict__ P1, const float* __restrict__ U1,
    const float* __restrict__ U2, unsigned short* __restrict__ wbuf)
{
    int t = blockIdx.x * 256 + threadIdx.x;
    if (t >= WBUF_ELEMS) return;
    const float* W; int e, Kreal;
    if (t < W2S_OFF)      { W = W1; e = t;            Kreal = 132; }
    else if (t < P1S_OFF) { W = W2; e = t - W2S_OFF;  Kreal = 64; }
    else if (t < U1S_OFF) { W = P1; e = t - P1S_OFF;  Kreal = 64; }
    else if (t < U2S_OFF) { W = U1; e = t - U1S_OFF;  Kreal = 128; }
    else                  { W = U2; e = t - U2S_OFF;  Kreal = 64; }
    int j = e & 7, lane = (e >> 3) & 63, nt = (e >> 9) & 3, kk = e >> 11;
    int k = kk * 32 + ((lane >> 4) * 8) + j;
    int n = nt * 16 + (lane & 15);
    float v = (k < Kreal) ? W[k * 64 + n] : 0.f;
    wbuf[t] = f2b(v);
}

// ---------------------------------------------------------------------------
// K1: per-(b,e) geometric invariants (unchanged from round 1)
// ---------------------------------------------------------------------------
__global__ __launch_bounds__(256) void geom_kernel(
    const float* __restrict__ pos, const int* __restrict__ ei,
    const int* __restrict__ cni, const float* __restrict__ mask,
    float* __restrict__ inv4)
{
    int tid = blockIdx.x * 256 + threadIdx.x;
    if (tid >= B_ * E_) return;
    int b = tid / E_;
    int e = tid - b * E_;
    int s = ei[e];
    int d = ei[E_ + e];
    const float* pb = pos + (size_t)b * C_ * P_;

    float rx = pb[s*3+0] - pb[d*3+0];
    float ry = pb[s*3+1] - pb[d*3+1];
    float rz = pb[s*3+2] - pb[d*3+2];
    float dist = sqrtf(rx*rx + ry*ry + rz*rz);

    float spx[M_], spy[M_], spz[M_], dpx[M_], dpy[M_], dpz[M_];
    float mx[M_], my[M_], sp2[M_], dp2[M_];
    #pragma unroll
    for (int m = 0; m < M_; ++m) {
        int ns = cni[s*M_ + m];
        spx[m] = pb[ns*3+0]; spy[m] = pb[ns*3+1]; spz[m] = pb[ns*3+2];
        int nd = cni[d*M_ + m];
        dpx[m] = pb[nd*3+0]; dpy[m] = pb[nd*3+1]; dpz[m] = pb[nd*3+2];
        mx[m] = mask[s*M_ + m];
        my[m] = mask[d*M_ + m];
        sp2[m] = spx[m]*spx[m] + spy[m]*spy[m] + spz[m]*spz[m];
        dp2[m] = dpx[m]*dpx[m] + dpy[m]*dpy[m] + dpz[m]*dpz[m];
    }
    const float INFV = __builtin_inff();
    float pair = 0.f, hxy = 0.f;
    float colmin[M_];
    #pragma unroll
    for (int j = 0; j < M_; ++j) colmin[j] = INFV;
    #pragma unroll
    for (int i = 0; i < M_; ++i) {
        float rowmin = INFV;
        #pragma unroll
        for (int j = 0; j < M_; ++j) {
            float cr = spx[i]*dpx[j] + spy[i]*dpy[j] + spz[i]*dpz[j];
            float dd = sqrtf(fmaxf(sp2[i] + dp2[j] - 2.f*cr, 0.f) + EPS_);
            pair += dd * mx[i] * my[j];
            rowmin    = (my[j] > 0.f) ? fminf(rowmin, dd)    : rowmin;
            colmin[j] = (mx[i] > 0.f) ? fminf(colmin[j], dd) : colmin[j];
        }
        hxy = fmaxf(hxy, (mx[i] > 0.f) ? rowmin : 0.f);
    }
    float hyx = 0.f;
    #pragma unroll
    for (int j = 0; j < M_; ++j)
        hyx = fmaxf(hyx, (my[j] > 0.f) ? colmin[j] : 0.f);
    float haus = fmaxf(hxy, hyx);

    float smx = 0.f, smy = 0.f;
    float cxx=0.f, cxy=0.f, cxz=0.f, cyx=0.f, cyy=0.f, cyz=0.f;
    #pragma unroll
    for (int m = 0; m < M_; ++m) {
        smx += mx[m]; smy += my[m];
        cxx += spx[m]*mx[m]; cxy += spy[m]*mx[m]; cxz += spz[m]*mx[m];
        cyx += dpx[m]*my[m]; cyy += dpy[m]*my[m]; cyz += dpz[m]*my[m];
    }
    float idx_ = 1.f / fmaxf(smx, EPS_);
    float idy_ = 1.f / fmaxf(smy, EPS_);
    float ddx = cxx*idx_ - cyx*idy_;
    float ddy = cxy*idx_ - cyy*idy_;
    float ddz = cxz*idx_ - cyz*idy_;
    float centroid = sqrtf(ddx*ddx + ddy*ddy + ddz*ddz);

    ((float4*)inv4)[(size_t)b * E_ + e] = make_float4(dist, pair, centroid, haus);
}

// ---------------------------------------------------------------------------
// K2: edge MLPs via MFMA bf16 16x16x32. 256 thr/block = 4 waves, 64 edges.
// Wave w owns edge rows [w*16, w*16+16). X LDS stride 168 elem -> 2-way banks.
// ---------------------------------------------------------------------------
__global__ __launch_bounds__(256) void edge_kernel(
    const float* __restrict__ feat, const float* __restrict__ pos,
    const int* __restrict__ ei, const float* __restrict__ inv4,
    const unsigned short* __restrict__ wbuf,
    const float* __restrict__ b1, const float* __restrict__ b2,
    const float* __restrict__ pb1, const float* __restrict__ P2,
    const float* __restrict__ pb2,
    float* __restrict__ agg, float* __restrict__ out_pos)
{
    __shared__ unsigned short Xl[64 * 168];
    __shared__ unsigned short Hl[64 * 72];
    __shared__ unsigned short Ml[64 * 72];

    const int tid  = threadIdx.x;
    const int w    = tid >> 6;
    const int lane = tid & 63;
    const int q    = lane >> 4;
    const int l16  = lane & 15;

    const int tile = blockIdx.x;
    const int b    = tile / (E_ / 64);
    const int e0   = (tile % (E_ / 64)) * 64;
    const int s_l  = ei[e0 + lane];
    const int d_l  = ei[E_ + e0 + lane];
    const float* fb = feat + (size_t)b * C_ * H_;

    // ---- stage X = [h_src | h_dst | inv4 | zeros] as bf16, wave-private rows
    for (int rr = 0; rr < 16; ++rr) {
        int r = w * 16 + rr;
        int sr = __shfl(s_l, r);
        int dr = __shfl(d_l, r);
        Xl[r*168 + lane]      = f2b(fb[(size_t)sr * 64 + lane]);
        Xl[r*168 + 64 + lane] = f2b(fb[(size_t)dr * 64 + lane]);
        if (lane < 36) {
            float v = 0.f;
            if (lane < 4) v = inv4[((size_t)b * E_ + e0 + r) * 4 + lane];
            Xl[r*168 + 128 + lane] = f2b(v);
        }
    }
    __syncthreads();

    // ---- layer 1: D1[16x64] = X @ W1 + b1  (5 kk x 4 nt MFMA)
    const unsigned short* W1s = wbuf + W1S_OFF;
    float4v acc[4];
    #pragma unroll
    for (int nt = 0; nt < 4; ++nt) {
        float bv = b1[nt*16 + l16];
        acc[nt] = (float4v){bv, bv, bv, bv};
    }
    const int arow = w * 16 + l16;
    #pragma unroll
    for (int kk = 0; kk < 5; ++kk) {
        short8 a = *(const short8*)&Xl[arow*168 + kk*32 + q*8];
        #pragma unroll
        for (int nt = 0; nt < 4; ++nt) {
            short8 bf = *(const short8*)&W1s[(((kk*4 + nt)*64) + lane) * 8];
            acc[nt] = __builtin_amdgcn_mfma_f32_16x16x32_bf16(a, bf, acc[nt], 0, 0, 0);
        }
    }
    // silu -> H (bf16), C/D layout: row=(q*4+i), col=nt*16+l16
    #pragma unroll
    for (int nt = 0; nt < 4; ++nt)
        #pragma unroll
        for (int i = 0; i < 4; ++i)
            Hl[(w*16 + q*4 + i)*72 + nt*16 + l16] = f2b(silu_(acc[nt][i]));
    __syncthreads();

    // ---- layer 2: M[16x64] = H @ W2 + b2  (2 kk x 4 nt)
    const unsigned short* W2s = wbuf + W2S_OFF;
    float4v mac[4];
    #pragma unroll
    for (int nt = 0; nt < 4; ++nt) {
        float bv = b2[nt*16 + l16];
        mac[nt] = (float4v){bv, bv, bv, bv};
    }
    #pragma unroll
    for (int kk = 0; kk < 2; ++kk) {
        short8 a = *(const short8*)&Hl[arow*72 + kk*32 + q*8];
        #pragma unroll
        for (int nt = 0; nt < 4; ++nt) {
            short8 bf = *(const short8*)&W2s[(((kk*4 + nt)*64) + lane) * 8];
            mac[nt] = __builtin_amdgcn_mfma_f32_16x16x32_bf16(a, bf, mac[nt], 0, 0, 0);
        }
    }
    #pragma unroll
    for (int nt = 0; nt < 4; ++nt)
        #pragma unroll
        for (int i = 0; i < 4; ++i)
            Ml[(w*16 + q*4 + i)*72 + nt*16 + l16] = f2b(mac[nt][i]);
    __syncthreads();

    // ---- gate: wt = tanh(silu(M @ P1 + pb1) @ P2 + pb2)
    const unsigned short* P1s = wbuf + P1S_OFF;
    float4v gac[4];
    #pragma unroll
    for (int nt = 0; nt < 4; ++nt) {
        float bv = pb1[nt*16 + l16];
        gac[nt] = (float4v){bv, bv, bv, bv};
    }
    #pragma unroll
    for (int kk = 0; kk < 2; ++kk) {
        short8 a = *(const short8*)&Ml[arow*72 + kk*32 + q*8];
        #pragma unroll
        for (int nt = 0; nt < 4; ++nt) {
            short8 bf = *(const short8*)&P1s[(((kk*4 + nt)*64) + lane) * 8];
            gac[nt] = __builtin_amdgcn_mfma_f32_16x16x32_bf16(a, bf, gac[nt], 0, 0, 0);
        }
    }
    float p2v[4];
    #pragma unroll
    for (int nt = 0; nt < 4; ++nt) p2v[nt] = P2[nt*16 + l16];
    const float pb2v = pb2[0];

    float* aggb = agg + (size_t)b * C_ * H_;
    float* opb  = out_pos + (size_t)b * C_ * P_;
    const float* pp = pos + (size_t)b * C_ * P_;

    #pragma unroll
    for (int i = 0; i < 4; ++i) {
        float p = 0.f;
        #pragma unroll
        for (int nt = 0; nt < 4; ++nt) p += silu_(gac[nt][i]) * p2v[nt];
        p += __shfl_xor(p, 8);
        p += __shfl_xor(p, 4);
        p += __shfl_xor(p, 2);
        p += __shfl_xor(p, 1);           // all 16 lanes of the quad have the sum
        float wt = tanhf(p + pb2v);
        int r  = w*16 + q*4 + i;
        int sr = __shfl(s_l, r);
        int dr = __shfl(d_l, r);
        if (l16 < 3) {
            float rel = pp[sr*3 + l16] - pp[dr*3 + l16];
            atomicAdd(&opb[dr*3 + l16], wt * rel);
        }
    }

    // ---- message scatter: coalesced 256B row atomics
    for (int rr = 0; rr < 16; ++rr) {
        int r  = w*16 + rr;
        int dr = __shfl(d_l, r);
        float mv = b2f(Ml[r*72 + lane]);
        atomicAdd(&aggb[(size_t)dr*64 + lane], mv);
    }
}

// ---------------------------------------------------------------------------
// K3: node update via MFMA. 256 thr/block, 64 rows, wave-private 16-row strips.
// new_features = features + MLP([features, agg/max(deg,1)])
// ---------------------------------------------------------------------------
__global__ __launch_bounds__(256) void node_kernel(
    const float* __restrict__ feat, const float* __restrict__ agg,
    const float* __restrict__ deg, const unsigned short* __restrict__ wbuf,
    const float* __restrict__ ub1, const float* __restrict__ ub2,
    float* __restrict__ out_feat)
{
    __shared__ unsigned short Xl[64 * 136];
    __shared__ unsigned short Hl[64 * 72];

    const int tid  = threadIdx.x;
    const int w    = tid >> 6;
    const int lane = tid & 63;
    const int q    = lane >> 4;
    const int l16  = lane & 15;
    const int g0   = blockIdx.x * 64;

    for (int rr = 0; rr < 16; ++rr) {
        int r = w * 16 + rr;
        int g = g0 + r;
        float sc = 1.f / fmaxf(deg[g % C_], 1.f);
        Xl[r*136 + lane]      = f2b(feat[(size_t)g*64 + lane]);
        Xl[r*136 + 64 + lane] = f2b(agg[(size_t)g*64 + lane] * sc);
    }
    __syncthreads();

    const unsigned short* U1s = wbuf + U1S_OFF;
    float4v acc[4];
    #pragma unroll
    for (int nt = 0; nt < 4; ++nt) {
        float bv = ub1[nt*16 + l16];
        acc[nt] = (float4v){bv, bv, bv, bv};
    }
    const int arow = w * 16 + l16;
    #pragma unroll
    for (int kk = 0; kk < 4; ++kk) {
        short8 a = *(const short8*)&Xl[arow*136 + kk*32 + q*8];
        #pragma unroll
        for (int nt = 0; nt < 4; ++nt) {
            short8 bf = *(const short8*)&U1s[(((kk*4 + nt)*64) + lane) * 8];
            acc[nt] = __builtin_amdgcn_mfma_f32_16x16x32_bf16(a, bf, acc[nt], 0, 0, 0);
        }
    }
    #pragma unroll
    for (int nt = 0; nt < 4; ++nt)
        #pragma unroll
        for (int i = 0; i < 4; ++i)
            Hl[(w*16 + q*4 + i)*72 + nt*16 + l16] = f2b(silu_(acc[nt][i]));
    __syncthreads();

    const unsigned short* U2s = wbuf + U2S_OFF;
    float4v oac[4];
    #pragma unroll
    for (int nt = 0; nt < 4; ++nt) {
        float bv = ub2[nt*16 + l16];
        oac[nt] = (float4v){bv, bv, bv, bv};
    }
    #pragma unroll
    for (int kk = 0; kk < 2; ++kk) {
        short8 a = *(const short8*)&Hl[arow*72 + kk*32 + q*8];
        #pragma unroll
        for (int nt = 0; nt < 4; ++nt) {
            short8 bf = *(const short8*)&U2s[(((kk*4 + nt)*64) + lane) * 8];
            oac[nt] = __builtin_amdgcn_mfma_f32_16x16x32_bf16(a, bf, oac[nt], 0, 0, 0);
        }
    }
    #pragma unroll
    for (int nt = 0; nt < 4; ++nt)
        #pragma unroll
        for (int i = 0; i < 4; ++i) {
            size_t idx = (size_t)(g0 + w*16 + q*4 + i) * 64 + nt*16 + l16;
            out_feat[idx] = feat[idx] + oac[nt][i];
        }
}

extern "C" void kernel_launch(void* const* d_in, const int* in_sizes, int n_in,
                              void* d_out, int out_size, void* d_ws, size_t ws_size,
                              hipStream_t stream) {
    const float* feat = (const float*)d_in[0];
    const float* pos  = (const float*)d_in[1];
    const int*   ei   = (const int*)d_in[2];
    const float* deg  = (const float*)d_in[3];
    const int*   cni  = (const int*)d_in[4];
    const float* mask = (const float*)d_in[5];
    const float* W1   = (const float*)d_in[6];
    const float* b1   = (const float*)d_in[7];
    const float* W2   = (const float*)d_in[8];
    const float* b2   = (const float*)d_in[9];
    const float* P1   = (const float*)d_in[10];
    const float* pb1  = (const float*)d_in[11];
    const float* P2   = (const float*)d_in[12];
    const float* pb2  = (const float*)d_in[13];
    const float* U1   = (const float*)d_in[14];
    const float* ub1  = (const float*)d_in[15];
    const float* U2   = (const float*)d_in[16];
    const float* ub2  = (const float*)d_in[17];

    float* out_feat = (float*)d_out;                       // B*C*H
    float* out_pos  = out_feat + (size_t)B_ * C_ * H_;     // B*C*P

    float* inv4 = (float*)d_ws;
    float* agg  = inv4 + (size_t)B_ * E_ * 4;
    unsigned short* wbuf = (unsigned short*)(agg + (size_t)B_ * C_ * H_);

    hipMemsetAsync(agg, 0, (size_t)B_ * C_ * H_ * sizeof(float), stream);
    hipMemcpyAsync(out_pos, pos, (size_t)B_ * C_ * P_ * sizeof(float),
                   hipMemcpyDeviceToDevice, stream);

    prep_kernel<<<(WBUF_ELEMS + 255) / 256, 256, 0, stream>>>(W1, W2, P1, U1, U2, wbuf);

    geom_kernel<<<(B_ * E_ + 255) / 256, 256, 0, stream>>>(pos, ei, cni, mask, inv4);

    edge_kernel<<<(B_ * E_) / 64, 256, 0, stream>>>(
        feat, pos, ei, inv4, wbuf, b1, b2, pb1, P2, pb2, agg, out_pos);

    node_kernel<<<(B_ * C_) / 64, 256, 0, stream>>>(
        feat, agg, deg, wbuf, ub1, ub2, out_feat);
}

// Round 3
// 274.130 us; speedup vs baseline: 2.0623x; 1.1670x over previous
//
#include <hip/hip_runtime.h>
#include <hip/hip_bf16.h>

#define B_ 2
#define C_ 20000
#define H_ 64
#define M_ 8
#define E_ 200000
#define P_ 3
#define EPS_ 1e-12f

typedef __attribute__((ext_vector_type(8))) short short8;
typedef __attribute__((ext_vector_type(4))) float float4v;

__device__ __forceinline__ float silu_(float x) {
    return x / (1.f + __expf(-x));
}
__device__ __forceinline__ unsigned short f2b(float f) {
    unsigned u = __float_as_uint(f);
    unsigned r = (u + 0x7FFF + ((u >> 16) & 1)) >> 16;   // RNE fp32->bf16
    return (unsigned short)r;
}
__device__ __forceinline__ float b2f(unsigned short h) {
    return __uint_as_float(((unsigned)h) << 16);
}
__device__ __forceinline__ uint2 pk4(float a, float b, float c, float d) {
    return make_uint2((unsigned)f2b(a) | ((unsigned)f2b(b) << 16),
                      (unsigned)f2b(c) | ((unsigned)f2b(d) << 16));
}

// workspace: inv4 (B*E*4 fp32) | agg (B*C*H fp32) | wbuf (28672 bf16)
// wbuf: B-fragment-swizzled weights, all K multiples of 32 (W1 only k<128;
// rows 128..131 of W1 applied in fp32 on the VALU).
#define W1S_OFF 0
#define W2S_OFF 8192
#define P1S_OFF 12288
#define U1S_OFF 16384
#define U2S_OFF 24576
#define WBUF_ELEMS 28672

__global__ __launch_bounds__(256) void prep_kernel(
    const float* __restrict__ W1, const float* __restrict__ W2,
    const float* __restrict__ P1, const float* __restrict__ U1,
    const float* __restrict__ U2, unsigned short* __restrict__ wbuf)
{
    int t = blockIdx.x * 256 + threadIdx.x;
    if (t >= WBUF_ELEMS) return;
    const float* W; int e;
    if (t < W2S_OFF)      { W = W1; e = t; }
    else if (t < U1S_OFF) { W = (t < P1S_OFF) ? W2 : P1; e = (t < P1S_OFF) ? t - W2S_OFF : t - P1S_OFF; }
    else if (t < U2S_OFF) { W = U1; e = t - U1S_OFF; }
    else                  { W = U2; e = t - U2S_OFF; }
    int j = e & 7, lane = (e >> 3) & 63, nt = (e >> 9) & 3, kk = e >> 11;
    int k = kk * 32 + ((lane >> 4) * 8) + j;
    int n = nt * 16 + (lane & 15);
    wbuf[t] = f2b(W[k * 64 + n]);
}

// ---------------------------------------------------------------------------
// K1: per-(b,e) geometric invariants
// ---------------------------------------------------------------------------
__global__ __launch_bounds__(256) void geom_kernel(
    const float* __restrict__ pos, const int* __restrict__ ei,
    const int* __restrict__ cni, const float* __restrict__ mask,
    float* __restrict__ inv4)
{
    int tid = blockIdx.x * 256 + threadIdx.x;
    if (tid >= B_ * E_) return;
    int b = tid / E_;
    int e = tid - b * E_;
    int s = ei[e];
    int d = ei[E_ + e];
    const float* pb = pos + (size_t)b * C_ * P_;

    float rx = pb[s*3+0] - pb[d*3+0];
    float ry = pb[s*3+1] - pb[d*3+1];
    float rz = pb[s*3+2] - pb[d*3+2];
    float dist = sqrtf(rx*rx + ry*ry + rz*rz);

    int4 ns0 = *(const int4*)&cni[s*M_];
    int4 ns1 = *(const int4*)&cni[s*M_ + 4];
    int4 nd0 = *(const int4*)&cni[d*M_];
    int4 nd1 = *(const int4*)&cni[d*M_ + 4];
    float4 mx0 = *(const float4*)&mask[s*M_];
    float4 mx1 = *(const float4*)&mask[s*M_ + 4];
    float4 my0 = *(const float4*)&mask[d*M_];
    float4 my1 = *(const float4*)&mask[d*M_ + 4];
    int nsi[M_] = {ns0.x, ns0.y, ns0.z, ns0.w, ns1.x, ns1.y, ns1.z, ns1.w};
    int ndi[M_] = {nd0.x, nd0.y, nd0.z, nd0.w, nd1.x, nd1.y, nd1.z, nd1.w};
    float mx[M_] = {mx0.x, mx0.y, mx0.z, mx0.w, mx1.x, mx1.y, mx1.z, mx1.w};
    float my[M_] = {my0.x, my0.y, my0.z, my0.w, my1.x, my1.y, my1.z, my1.w};

    float spx[M_], spy[M_], spz[M_], dpx[M_], dpy[M_], dpz[M_], sp2[M_], dp2[M_];
    #pragma unroll
    for (int m = 0; m < M_; ++m) {
        spx[m] = pb[nsi[m]*3+0]; spy[m] = pb[nsi[m]*3+1]; spz[m] = pb[nsi[m]*3+2];
        dpx[m] = pb[ndi[m]*3+0]; dpy[m] = pb[ndi[m]*3+1]; dpz[m] = pb[ndi[m]*3+2];
        sp2[m] = spx[m]*spx[m] + spy[m]*spy[m] + spz[m]*spz[m];
        dp2[m] = dpx[m]*dpx[m] + dpy[m]*dpy[m] + dpz[m]*dpz[m];
    }
    const float INFV = __builtin_inff();
    float pair = 0.f, hxy = 0.f;
    float colmin[M_];
    #pragma unroll
    for (int j = 0; j < M_; ++j) colmin[j] = INFV;
    #pragma unroll
    for (int i = 0; i < M_; ++i) {
        float rowmin = INFV;
        #pragma unroll
        for (int j = 0; j < M_; ++j) {
            float cr = spx[i]*dpx[j] + spy[i]*dpy[j] + spz[i]*dpz[j];
            float dd = sqrtf(fmaxf(sp2[i] + dp2[j] - 2.f*cr, 0.f) + EPS_);
            pair += dd * mx[i] * my[j];
            rowmin    = (my[j] > 0.f) ? fminf(rowmin, dd)    : rowmin;
            colmin[j] = (mx[i] > 0.f) ? fminf(colmin[j], dd) : colmin[j];
        }
        hxy = fmaxf(hxy, (mx[i] > 0.f) ? rowmin : 0.f);
    }
    float hyx = 0.f;
    #pragma unroll
    for (int j = 0; j < M_; ++j)
        hyx = fmaxf(hyx, (my[j] > 0.f) ? colmin[j] : 0.f);
    float haus = fmaxf(hxy, hyx);

    float smx = 0.f, smy = 0.f;
    float cxx=0.f, cxy=0.f, cxz=0.f, cyx=0.f, cyy=0.f, cyz=0.f;
    #pragma unroll
    for (int m = 0; m < M_; ++m) {
        smx += mx[m]; smy += my[m];
        cxx += spx[m]*mx[m]; cxy += spy[m]*mx[m]; cxz += spz[m]*mx[m];
        cyx += dpx[m]*my[m]; cyy += dpy[m]*my[m]; cyz += dpz[m]*my[m];
    }
    float idx_ = 1.f / fmaxf(smx, EPS_);
    float idy_ = 1.f / fmaxf(smy, EPS_);
    float ddx = cxx*idx_ - cyx*idy_;
    float ddy = cxy*idx_ - cyy*idy_;
    float ddz = cxz*idx_ - cyz*idy_;
    float centroid = sqrtf(ddx*ddx + ddy*ddy + ddz*ddz);

    ((float4*)inv4)[(size_t)b * E_ + e] = make_float4(dist, pair, centroid, haus);
}

// ---------------------------------------------------------------------------
// K2: edge MLPs via MFMA. 256 thr = 4 fully-independent waves x 16 edges.
// NO barriers: every LDS strip is wave-private; DS ops are in-order per wave.
// Per-wave arena (ushorts): X[16x136] at 0, H[16x72] at 2176, M aliases X.
// ---------------------------------------------------------------------------
__global__ __launch_bounds__(256) void edge_kernel(
    const float* __restrict__ feat, const float* __restrict__ pos,
    const int* __restrict__ ei, const float* __restrict__ inv4,
    const unsigned short* __restrict__ wbuf, const float* __restrict__ W1,
    const float* __restrict__ b1, const float* __restrict__ b2,
    const float* __restrict__ pb1, const float* __restrict__ P2,
    const float* __restrict__ pb2,
    float* __restrict__ agg, float* __restrict__ out_pos)
{
    __shared__ unsigned short lds[4 * 3328];   // 26624 B -> 6 blocks/CU

    const int tid  = threadIdx.x;
    const int w    = tid >> 6;
    const int lane = tid & 63;
    const int q    = lane >> 4;
    const int l16  = lane & 15;

    const int tile = blockIdx.x;
    const int b    = tile / (E_ / 64);
    const int e0   = (tile % (E_ / 64)) * 64;
    const int s_l  = ei[e0 + lane];
    const int d_l  = ei[E_ + e0 + lane];
    const float* fb = feat + (size_t)b * C_ * H_;

    unsigned short* Xw = lds + w * 3328;
    unsigned short* Hw = Xw + 2176;
    unsigned short* Mw = Xw;   // alias: X is dead before M is written (dep chain)

    // ---- stage X = [h_src | h_dst] bf16, 4 rows per float4 gather
    const int rr4 = lane >> 4, c4 = lane & 15;
    #pragma unroll
    for (int it = 0; it < 4; ++it) {
        int rloc = it * 4 + rr4;
        int r = w * 16 + rloc;
        int sr = __shfl(s_l, r);
        int dr = __shfl(d_l, r);
        float4 vs = *(const float4*)&fb[(size_t)sr * 64 + c4 * 4];
        float4 vd = *(const float4*)&fb[(size_t)dr * 64 + c4 * 4];
        *(uint2*)&Xw[rloc*136 + c4*4]      = pk4(vs.x, vs.y, vs.z, vs.w);
        *(uint2*)&Xw[rloc*136 + 64 + c4*4] = pk4(vd.x, vd.y, vd.z, vd.w);
    }

    // ---- layer 1: X(k<128) @ W1 via MFMA + fp32 invariant tail on VALU
    float4v acc[4];
    #pragma unroll
    for (int nt = 0; nt < 4; ++nt) {
        float bv = b1[nt*16 + l16];
        acc[nt] = (float4v){bv, bv, bv, bv};
    }
    #pragma unroll
    for (int kk = 0; kk < 4; ++kk) {
        short8 a = *(const short8*)&Xw[l16*136 + kk*32 + q*8];
        #pragma unroll
        for (int nt = 0; nt < 4; ++nt) {
            short8 bf = *(const short8*)&wbuf[W1S_OFF + (((kk*4 + nt)*64) + lane) * 8];
            acc[nt] = __builtin_amdgcn_mfma_f32_16x16x32_bf16(a, bf, acc[nt], 0, 0, 0);
        }
    }
    float4 iv[4];
    #pragma unroll
    for (int i = 0; i < 4; ++i)
        iv[i] = ((const float4*)inv4)[(size_t)b * E_ + e0 + w*16 + q*4 + i];
    #pragma unroll
    for (int nt = 0; nt < 4; ++nt) {
        float wa = W1[128*64 + nt*16 + l16];
        float wb = W1[129*64 + nt*16 + l16];
        float wc = W1[130*64 + nt*16 + l16];
        float wd = W1[131*64 + nt*16 + l16];
        #pragma unroll
        for (int i = 0; i < 4; ++i)
            acc[nt][i] += iv[i].x*wa + iv[i].y*wb + iv[i].z*wc + iv[i].w*wd;
    }
    #pragma unroll
    for (int nt = 0; nt < 4; ++nt)
        #pragma unroll
        for (int i = 0; i < 4; ++i)
            Hw[(q*4 + i)*72 + nt*16 + l16] = f2b(silu_(acc[nt][i]));

    // ---- layer 2 -> messages
    float4v mac[4];
    #pragma unroll
    for (int nt = 0; nt < 4; ++nt) {
        float bv = b2[nt*16 + l16];
        mac[nt] = (float4v){bv, bv, bv, bv};
    }
    #pragma unroll
    for (int kk = 0; kk < 2; ++kk) {
        short8 a = *(const short8*)&Hw[l16*72 + kk*32 + q*8];
        #pragma unroll
        for (int nt = 0; nt < 4; ++nt) {
            short8 bf = *(const short8*)&wbuf[W2S_OFF + (((kk*4 + nt)*64) + lane) * 8];
            mac[nt] = __builtin_amdgcn_mfma_f32_16x16x32_bf16(a, bf, mac[nt], 0, 0, 0);
        }
    }
    #pragma unroll
    for (int nt = 0; nt < 4; ++nt)
        #pragma unroll
        for (int i = 0; i < 4; ++i)
            Mw[(q*4 + i)*72 + nt*16 + l16] = f2b(mac[nt][i]);

    // ---- gate: wt = tanh(silu(M @ P1 + pb1) @ P2 + pb2)
    float4v gac[4];
    #pragma unroll
    for (int nt = 0; nt < 4; ++nt) {
        float bv = pb1[nt*16 + l16];
        gac[nt] = (float4v){bv, bv, bv, bv};
    }
    #pragma unroll
    for (int kk = 0; kk < 2; ++kk) {
        short8 a = *(const short8*)&Mw[l16*72 + kk*32 + q*8];
        #pragma unroll
        for (int nt = 0; nt < 4; ++nt) {
            short8 bf = *(const short8*)&wbuf[P1S_OFF + (((kk*4 + nt)*64) + lane) * 8];
            gac[nt] = __builtin_amdgcn_mfma_f32_16x16x32_bf16(a, bf, gac[nt], 0, 0, 0);
        }
    }
    float p2v[4];
    #pragma unroll
    for (int nt = 0; nt < 4; ++nt) p2v[nt] = P2[nt*16 + l16];
    const float pb2v = pb2[0];

    float* aggb = agg + (size_t)b * C_ * H_;
    float* opb  = out_pos + (size_t)b * C_ * P_;
    const float* pp = pos + (size_t)b * C_ * P_;

    #pragma unroll
    for (int i = 0; i < 4; ++i) {
        float p = 0.f;
        #pragma unroll
        for (int nt = 0; nt < 4; ++nt) p += silu_(gac[nt][i]) * p2v[nt];
        p += __shfl_xor(p, 8);
        p += __shfl_xor(p, 4);
        p += __shfl_xor(p, 2);
        p += __shfl_xor(p, 1);
        float wt = tanhf(p + pb2v);
        int r  = w*16 + q*4 + i;
        int sr = __shfl(s_l, r);
        int dr = __shfl(d_l, r);
        if (l16 < 3) {
            float rel = pp[sr*3 + l16] - pp[dr*3 + l16];
            atomicAdd(&opb[dr*3 + l16], wt * rel);
        }
    }

    // ---- message scatter: coalesced 256B row atomics
    #pragma unroll
    for (int rr = 0; rr < 16; ++rr) {
        int r  = w*16 + rr;
        int dr = __shfl(d_l, r);
        float mv = b2f(Mw[rr*72 + lane]);
        atomicAdd(&aggb[(size_t)dr*64 + lane], mv);
    }
}

// ---------------------------------------------------------------------------
// K3: node update via MFMA, barrier-free wave-private strips.
// ---------------------------------------------------------------------------
__global__ __launch_bounds__(256) void node_kernel(
    const float* __restrict__ feat, const float* __restrict__ agg,
    const float* __restrict__ deg, const unsigned short* __restrict__ wbuf,
    const float* __restrict__ ub1, const float* __restrict__ ub2,
    float* __restrict__ out_feat)
{
    __shared__ unsigned short lds[4 * 3328];

    const int tid  = threadIdx.x;
    const int w    = tid >> 6;
    const int lane = tid & 63;
    const int q    = lane >> 4;
    const int l16  = lane & 15;
    const int g0   = blockIdx.x * 64;

    unsigned short* Xw = lds + w * 3328;
    unsigned short* Hw = Xw + 2176;

    const int rr4 = lane >> 4, c4 = lane & 15;
    #pragma unroll
    for (int it = 0; it < 4; ++it) {
        int rloc = it * 4 + rr4;
        int g = g0 + w*16 + rloc;
        int gc = (g >= C_) ? g - C_ : g;
        float sc = 1.f / fmaxf(deg[gc], 1.f);
        float4 vf = *(const float4*)&feat[(size_t)g * 64 + c4 * 4];
        float4 va = *(const float4*)&agg[(size_t)g * 64 + c4 * 4];
        *(uint2*)&Xw[rloc*136 + c4*4]      = pk4(vf.x, vf.y, vf.z, vf.w);
        *(uint2*)&Xw[rloc*136 + 64 + c4*4] = pk4(va.x*sc, va.y*sc, va.z*sc, va.w*sc);
    }

    float4v acc[4];
    #pragma unroll
    for (int nt = 0; nt < 4; ++nt) {
        float bv = ub1[nt*16 + l16];
        acc[nt] = (float4v){bv, bv, bv, bv};
    }
    #pragma unroll
    for (int kk = 0; kk < 4; ++kk) {
        short8 a = *(const short8*)&Xw[l16*136 + kk*32 + q*8];
        #pragma unroll
        for (int nt = 0; nt < 4; ++nt) {
            short8 bf = *(const short8*)&wbuf[U1S_OFF + (((kk*4 + nt)*64) + lane) * 8];
            acc[nt] = __builtin_amdgcn_mfma_f32_16x16x32_bf16(a, bf, acc[nt], 0, 0, 0);
        }
    }
    #pragma unroll
    for (int nt = 0; nt < 4; ++nt)
        #pragma unroll
        for (int i = 0; i < 4; ++i)
            Hw[(q*4 + i)*72 + nt*16 + l16] = f2b(silu_(acc[nt][i]));

    float4v oac[4];
    #pragma unroll
    for (int nt = 0; nt < 4; ++nt) {
        float bv = ub2[nt*16 + l16];
        oac[nt] = (float4v){bv, bv, bv, bv};
    }
    #pragma unroll
    for (int kk = 0; kk < 2; ++kk) {
        short8 a = *(const short8*)&Hw[l16*72 + kk*32 + q*8];
        #pragma unroll
        for (int nt = 0; nt < 4; ++nt) {
            short8 bf = *(const short8*)&wbuf[U2S_OFF + (((kk*4 + nt)*64) + lane) * 8];
            oac[nt] = __builtin_amdgcn_mfma_f32_16x16x32_bf16(a, bf, oac[nt], 0, 0, 0);
        }
    }
    #pragma unroll
    for (int nt = 0; nt < 4; ++nt)
        #pragma unroll
        for (int i = 0; i < 4; ++i) {
            size_t idx = (size_t)(g0 + w*16 + q*4 + i) * 64 + nt*16 + l16;
            out_feat[idx] = feat[idx] + oac[nt][i];
        }
}

extern "C" void kernel_launch(void* const* d_in, const int* in_sizes, int n_in,
                              void* d_out, int out_size, void* d_ws, size_t ws_size,
                              hipStream_t stream) {
    const float* feat = (const float*)d_in[0];
    const float* pos  = (const float*)d_in[1];
    const int*   ei   = (const int*)d_in[2];
    const float* deg  = (const float*)d_in[3];
    const int*   cni  = (const int*)d_in[4];
    const float* mask = (const float*)d_in[5];
    const float* W1   = (const float*)d_in[6];
    const float* b1   = (const float*)d_in[7];
    const float* W2   = (const float*)d_in[8];
    const float* b2   = (const float*)d_in[9];
    const float* P1   = (const float*)d_in[10];
    const float* pb1  = (const float*)d_in[11];
    const float* P2   = (const float*)d_in[12];
    const float* pb2  = (const float*)d_in[13];
    const float* U1   = (const float*)d_in[14];
    const float* ub1  = (const float*)d_in[15];
    const float* U2   = (const float*)d_in[16];
    const float* ub2  = (const float*)d_in[17];

    float* out_feat = (float*)d_out;                       // B*C*H
    float* out_pos  = out_feat + (size_t)B_ * C_ * H_;     // B*C*P

    float* inv4 = (float*)d_ws;
    float* agg  = inv4 + (size_t)B_ * E_ * 4;
    unsigned short* wbuf = (unsigned short*)(agg + (size_t)B_ * C_ * H_);

    hipMemsetAsync(agg, 0, (size_t)B_ * C_ * H_ * sizeof(float), stream);
    hipMemcpyAsync(out_pos, pos, (size_t)B_ * C_ * P_ * sizeof(float),
                   hipMemcpyDeviceToDevice, stream);

    prep_kernel<<<(WBUF_ELEMS + 255) / 256, 256, 0, stream>>>(W1, W2, P1, U1, U2, wbuf);

    geom_kernel<<<(B_ * E_ + 255) / 256, 256, 0, stream>>>(pos, ei, cni, mask, inv4);

    edge_kernel<<<(B_ * E_) / 64, 256, 0, stream>>>(
        feat, pos, ei, inv4, wbuf, W1, b1, b2, pb1, P2, pb2, agg, out_pos);

    node_kernel<<<(B_ * C_) / 64, 256, 0, stream>>>(
        feat, agg, deg, wbuf, ub1, ub2, out_feat);
}